// Round 14
// baseline (40.676 us; speedup 1.0000x reference)
//
#include <hip/hip_runtime.h>

// ChamferLoss via 32x32x16 MFMA: preds (8,3,2048,8) f32, gts (8,3,2048) f32, idx (64,2).
// P[i][j] = rx_i + ry_j - 2 x_i.y_j inside one mfma_f32_32x32x16_bf16 per tile via
// split-bf16 K-packing (13/16 slots). R14: col-half split -> grid 2048 blocks
// (100% thread-occupancy cap, was 50%); per-wave chain halves. Row mins become
// 2-way partials merged in reduce1n. Reg double-buffer + setprio kept from R13.

#define NPTS 2048
#define NB 64
#define BLK 256

#define PREDS_A 49152
#define PREDS_C 16384
#define GTS_A 6144
#define GTS_C 2048

// ---- main-path ws layout ----
#define OFF_ROW   0                        // rowpart: 2*64*2048*4 = 1 MB
#define OFF_CPART 1048576                  // colpart: 16*64*2048*4 = 8 MB
#define OFF_PART  9437184                  // partial: 256 floats
#define OFF_QPK   9441280                  // 4 MB
#define OFF_YPK   13635584                 // 4 MB
#define WS_REQ    17829888

using bf16x8  = __attribute__((ext_vector_type(8))) __bf16;
using short8v = __attribute__((ext_vector_type(8))) short;
using f32x16  = __attribute__((ext_vector_type(16))) float;

static __device__ __forceinline__ unsigned short f2bf(float f) {
    unsigned u = __float_as_uint(f);
    u = u + 0x7FFFu + ((u >> 16) & 1u);      // RNE
    return (unsigned short)(u >> 16);
}
static __device__ __forceinline__ float bf2f(unsigned short h) {
    return __uint_as_float(((unsigned)h) << 16);
}
static __device__ __forceinline__ float min3f(float a, float b, float c) {
    return fminf(fminf(a, b), c);            // clang fuses to v_min3_f32
}
static __device__ __forceinline__ float ctree(f32x16 a) {
    const float c0 = min3f(a[0], a[1], a[2]);
    const float c1 = min3f(a[3], a[4], a[5]);
    const float c2 = min3f(a[6], a[7], a[8]);
    const float c3 = min3f(a[9], a[10], a[11]);
    const float c4 = min3f(a[12], a[13], a[14]);
    const float d0 = min3f(c0, c1, a[15]);
    const float d1 = min3f(c2, c3, c4);
    return fminf(d0, d1);                    // 8 ops for 16 elems
}

// ---------- pack: 1024 blocks ----------
__global__ __launch_bounds__(256) void cf_pack2(
    const float* __restrict__ preds, const float* __restrict__ gts,
    const int* __restrict__ idx,
    unsigned short* __restrict__ qpk, unsigned short* __restrict__ ypk)
{
    const int blk = blockIdx.x, tid = threadIdx.x;
    const unsigned short one = 0x3F80;
    if (blk < 512) {                         // qpk[b][i] : A_k packing
        const int p = blk * 256 + tid;
        const int b = p >> 11, i = p & 2047;
        const int i0 = idx[2 * b], m1 = idx[2 * b + 1];
        const float* pb = preds + i0 * PREDS_A + m1 + i * 8;
        const float x0 = pb[0], x1 = pb[PREDS_C], x2 = pb[2 * PREDS_C];
        const float rx = fmaf(x0, x0, fmaf(x1, x1, x2 * x2));
        const float a0 = -2.f * x0, a1 = -2.f * x1, a2 = -2.f * x2;
        const unsigned short h0 = f2bf(a0), h1 = f2bf(a1), h2 = f2bf(a2);
        const unsigned short l0 = f2bf(a0 - bf2f(h0));
        const unsigned short l1 = f2bf(a1 - bf2f(h1));
        const unsigned short l2 = f2bf(a2 - bf2f(h2));
        const unsigned short rh = f2bf(rx), rl = f2bf(rx - bf2f(rh));
        alignas(16) unsigned short t[16] =
            {h0, h1, h2, h0, h1, h2, l0, l1, l2, rh, rl, one, one, 0, 0, 0};
        uint4* dst = (uint4*)(qpk + (size_t)p * 16);
        dst[0] = *(const uint4*)&t[0];
        dst[1] = *(const uint4*)&t[8];
    } else {                                 // ypk[b][j] : B_k packing
        const int p = (blk - 512) * 256 + tid;
        const int b = p >> 11, j = p & 2047;
        const int i0 = idx[2 * b];
        const float* gb = gts + i0 * GTS_A + j;
        const float y0 = gb[0], y1 = gb[GTS_C], y2 = gb[2 * GTS_C];
        const float ry = fmaf(y0, y0, fmaf(y1, y1, y2 * y2));
        const unsigned short h0 = f2bf(y0), h1 = f2bf(y1), h2 = f2bf(y2);
        const unsigned short l0 = f2bf(y0 - bf2f(h0));
        const unsigned short l1 = f2bf(y1 - bf2f(h1));
        const unsigned short l2 = f2bf(y2 - bf2f(h2));
        const unsigned short rh = f2bf(ry), rl = f2bf(ry - bf2f(rh));
        alignas(16) unsigned short t[16] =
            {h0, h1, h2, l0, l1, l2, h0, h1, h2, one, one, rh, rl, 0, 0, 0};
        uint4* dst = (uint4*)(ypk + (size_t)p * 16);
        dst[0] = *(const uint4*)&t[0];
        dst[1] = *(const uint4*)&t[8];
    }
}

// ---------- main: col-half split. grid = 64 b x 16 strips x 2 colhalves ----------
// Wave w owns rows strip*128 + w*32 .. +31, cols colhalf*1024 .. +1023 (16 pairs).
__global__ __launch_bounds__(BLK, 4) void cf_mf3d(
    const unsigned short* __restrict__ qpk, const unsigned short* __restrict__ ypk,
    float* __restrict__ rowpart, float* __restrict__ colpart)
{
    const int tid = threadIdx.x;
    const int bid = blockIdx.x;
    const int colhalf = bid & 1;
    const int strip = (bid >> 1) & 15;
    const int b = bid >> 5;

    __shared__ float scolw[4][1024];         // 16 KB; every slot written exactly once

    const int l = tid & 63, w = tid >> 6;
    const int lc = l & 31, lh = l >> 5;

    const short8v* qv = (const short8v*)qpk;
    const short8v* yv = (const short8v*)ypk;

    const int arow = b * NPTS + strip * 128 + w * 32 + lc;
    const bf16x8 afrag = __builtin_bit_cast(bf16x8, qv[arow * 2 + lh]);

    float rm[16];
#pragma unroll
    for (int r = 0; r < 16; ++r) rm[r] = INFINITY;

    const f32x16 z = {0.f, 0.f, 0.f, 0.f, 0.f, 0.f, 0.f, 0.f,
                      0.f, 0.f, 0.f, 0.f, 0.f, 0.f, 0.f, 0.f};

    const short8v* yp = yv + ((b * NPTS + colhalf * 1024) * 2 + lc * 2 + lh);

    // prologue: first B pair in flight
    bf16x8 curA = __builtin_bit_cast(bf16x8, yp[0]);
    bf16x8 curB = __builtin_bit_cast(bf16x8, yp[64]);

#pragma unroll 2
    for (int s = 0; s < 16; ++s) {
        const int nidx = (s < 15) ? (2 * s + 2) * 64 : 0;
        const bf16x8 nxtA = __builtin_bit_cast(bf16x8, yp[nidx]);
        const bf16x8 nxtB = __builtin_bit_cast(bf16x8, yp[nidx + 64]);

        __builtin_amdgcn_s_setprio(1);
        f32x16 accA = __builtin_amdgcn_mfma_f32_32x32x16_bf16(afrag, curA, z, 0, 0, 0);
        f32x16 accB = __builtin_amdgcn_mfma_f32_32x32x16_bf16(afrag, curB, z, 0, 0, 0);
        __builtin_amdgcn_s_setprio(0);

#pragma unroll
        for (int r = 0; r < 16; ++r) rm[r] = min3f(accA[r], accB[r], rm[r]);
        float cmA = ctree(accA);
        float cmB = ctree(accB);
        cmA = fminf(cmA, __shfl_xor(cmA, 32, 64));
        cmB = fminf(cmB, __shfl_xor(cmB, 32, 64));
        scolw[w][(2 * s) * 32 + lc] = cmA;
        scolw[w][(2 * s + 1) * 32 + lc] = cmB;

        curA = nxtA; curB = nxtB;
    }

    // ---- row flush: butterfly over 32 col-lanes, exclusive store to this half ----
#pragma unroll
    for (int r = 0; r < 16; ++r) {
        float v = rm[r];
        v = fminf(v, __shfl_xor(v, 1, 32));
        v = fminf(v, __shfl_xor(v, 2, 32));
        v = fminf(v, __shfl_xor(v, 4, 32));
        v = fminf(v, __shfl_xor(v, 8, 32));
        v = fminf(v, __shfl_xor(v, 16, 32));
        rm[r] = v;
    }
    if (lc == 0) {
        const int rbase = colhalf * (NB * NPTS) + b * NPTS + strip * 128 + w * 32 + 4 * lh;
#pragma unroll
        for (int r = 0; r < 16; ++r)
            rowpart[rbase + (r & 3) + 8 * (r >> 2)] = fmaxf(rm[r], 0.f);
    }

    // ---- col flush: min over 4 waves, exclusive store ----
    __syncthreads();
    float* cp = colpart + (size_t)strip * (NB * NPTS) + b * NPTS + colhalf * 1024;
    for (int k = tid; k < 1024; k += BLK) {
        const float m = fminf(fminf(scolw[0][k], scolw[1][k]),
                              fminf(scolw[2][k], scolw[3][k]));
        cp[k] = fmaxf(m, 0.f);
    }
}

// ---------- reduce: blocks 0-127 rows (merge 2 halves); 128-255 cols (16 strips) ----------
__global__ __launch_bounds__(256) void cf_reduce1n(
    const float* __restrict__ rowpart, const float* __restrict__ colpart,
    float* __restrict__ partial)
{
    __shared__ float sm[4];
    const int blk = blockIdx.x, tid = threadIdx.x;
    float s = 0.0f;
    if (blk < 128) {
        const int base = blk * 1024;
        for (int i = 0; i < 4; ++i) {
            const int g = base + tid + i * 256;
            s += fminf(rowpart[g], rowpart[NB * NPTS + g]);
        }
    } else {
        const int base = (blk - 128) * 1024;
        for (int i = 0; i < 4; ++i) {
            const int g = base + tid + i * 256;
            float m = INFINITY;
#pragma unroll
            for (int st = 0; st < 16; ++st)
                m = fminf(m, colpart[(size_t)st * (NB * NPTS) + g]);
            s += m;
        }
    }
#pragma unroll
    for (int off = 32; off > 0; off >>= 1)
        s += __shfl_down(s, off, 64);
    if ((tid & 63) == 0) sm[tid >> 6] = s;
    __syncthreads();
    if (tid == 0)
        partial[blk] = sm[0] + sm[1] + sm[2] + sm[3];
}

__global__ __launch_bounds__(256) void cf_reduce2n(const float* __restrict__ partial,
                                                   float* __restrict__ out) {
    __shared__ float sm[4];
    float s = partial[threadIdx.x];
#pragma unroll
    for (int off = 32; off > 0; off >>= 1)
        s += __shfl_down(s, off, 64);
    if ((threadIdx.x & 63) == 0) sm[threadIdx.x >> 6] = s;
    __syncthreads();
    if (threadIdx.x == 0)
        out[0] = (sm[0] + sm[1] + sm[2] + sm[3]) * (1.0f / 64.0f);
}

// ================= fallback (proven R6 path, uint-atomic based) =================
#define NMIN (2 * NB * NPTS)
#define FIT 128
#define FJT 128
#define PADI(j) ((j) + ((j) >> 4))

__global__ __launch_bounds__(256) void cf_init(unsigned* __restrict__ colbuf) {
    int i = blockIdx.x * 256 + threadIdx.x;
    colbuf[i] = 0x7F800000u;
}

__global__ __launch_bounds__(BLK, 4) void cf_tile_lds(
    const float* __restrict__ preds, const float* __restrict__ gts,
    const int* __restrict__ idx, unsigned* __restrict__ minbuf)
{
    const int tid = threadIdx.x;
    const int bid = blockIdx.x;
    const int it = bid & 15;
    const int b = bid >> 4;
    const int i0 = idx[2 * b];
    const int m1 = idx[2 * b + 1];
    const float* pbase = preds + i0 * PREDS_A + m1;
    const float* gbase = gts + i0 * GTS_A;

    __shared__ float4 sq[PADI(FIT - 1) + 2];
    __shared__ float4 sr[PADI(NPTS - 1) + 2];
    __shared__ float  scolw[4][FJT];

    if (tid < FIT) {
        const int i = it * FIT + tid;
        const float q0 = pbase[i * 8];
        const float q1 = pbase[i * 8 + PREDS_C];
        const float q2 = pbase[i * 8 + 2 * PREDS_C];
        const float rq = fmaf(q0, q0, fmaf(q1, q1, q2 * q2));
        sq[PADI(tid)] = make_float4(-2.f * q0, -2.f * q1, -2.f * q2, rq);
    }
#pragma unroll
    for (int k = 0; k < 8; ++k) {
        const int j = tid + BLK * k;
        const float r0 = gbase[j];
        const float r1 = gbase[j + GTS_C];
        const float r2 = gbase[j + 2 * GTS_C];
        const float rr = fmaf(r0, r0, fmaf(r1, r1, r2 * r2));
        sr[PADI(j)] = make_float4(r0, r1, r2, rr);
    }
    __syncthreads();

    const int ty = tid >> 4, tx = tid & 15;
    float nq0[8], nq1[8], nq2[8], rq[8], rmin[8];
#pragma unroll
    for (int u = 0; u < 8; ++u) {
        const float4 q = sq[PADI(ty * 8 + u)];
        nq0[u] = q.x; nq1[u] = q.y; nq2[u] = q.z; rq[u] = q.w;
        rmin[u] = INFINITY;
    }
    unsigned* rowbuf = minbuf;
    unsigned* colbuf = minbuf + NB * NPTS;

    for (int jt = 0; jt < NPTS / FJT; ++jt) {
        float4 r[8];
        const int rb = PADI(jt * FJT + tx * 8);
#pragma unroll
        for (int v = 0; v < 8; ++v) r[v] = sr[rb + v];
        float cmin[8];
#pragma unroll
        for (int v = 0; v < 8; ++v) cmin[v] = INFINITY;
#pragma unroll
        for (int v = 0; v < 8; v += 2) {
#pragma unroll
            for (int u = 0; u < 8; u += 2) {
                float s00 = fmaf(nq2[u], r[v].z, r[v].w);
                s00 = fmaf(nq1[u], r[v].y, s00);
                s00 = fmaf(nq0[u], r[v].x, s00);
                float s01 = fmaf(nq2[u], r[v + 1].z, r[v + 1].w);
                s01 = fmaf(nq1[u], r[v + 1].y, s01);
                s01 = fmaf(nq0[u], r[v + 1].x, s01);
                float s10 = fmaf(nq2[u + 1], r[v].z, r[v].w);
                s10 = fmaf(nq1[u + 1], r[v].y, s10);
                s10 = fmaf(nq0[u + 1], r[v].x, s10);
                float s11 = fmaf(nq2[u + 1], r[v + 1].z, r[v + 1].w);
                s11 = fmaf(nq1[u + 1], r[v + 1].y, s11);
                s11 = fmaf(nq0[u + 1], r[v + 1].x, s11);
                rmin[u]     = min3f(s00, s01, rmin[u]);
                rmin[u + 1] = min3f(s10, s11, rmin[u + 1]);
                const float d00 = s00 + rq[u];
                const float d10 = s10 + rq[u + 1];
                const float d01 = s01 + rq[u];
                const float d11 = s11 + rq[u + 1];
                cmin[v]     = min3f(d00, d10, cmin[v]);
                cmin[v + 1] = min3f(d01, d11, cmin[v + 1]);
            }
        }
#pragma unroll
        for (int v = 0; v < 8; ++v) {
            float c = cmin[v];
            c = fminf(c, __shfl_xor(c, 16, 64));
            c = fminf(c, __shfl_xor(c, 32, 64));
            cmin[v] = c;
        }
        if (((tid >> 4) & 3) == 0) {
            const int w = tid >> 6;
            *(float4*)&scolw[w][tx * 8]     = make_float4(cmin[0], cmin[1], cmin[2], cmin[3]);
            *(float4*)&scolw[w][tx * 8 + 4] = make_float4(cmin[4], cmin[5], cmin[6], cmin[7]);
        }
        __syncthreads();
        if (tid < FJT) {
            float m = fminf(min3f(scolw[0][tid], scolw[1][tid], scolw[2][tid]), scolw[3][tid]);
            m = fmaxf(m, 0.0f);
            atomicMin(&colbuf[b * NPTS + jt * FJT + tid], __float_as_uint(m));
        }
        __syncthreads();
    }
#pragma unroll
    for (int u = 0; u < 8; ++u) {
        float rm = rmin[u];
        rm = fminf(rm, __shfl_xor(rm, 1, 16));
        rm = fminf(rm, __shfl_xor(rm, 2, 16));
        rm = fminf(rm, __shfl_xor(rm, 4, 16));
        rm = fminf(rm, __shfl_xor(rm, 8, 16));
        rmin[u] = rm;
    }
    if (tx == 0) {
#pragma unroll
        for (int u = 0; u < 8; ++u) {
            const float d = fmaxf(rmin[u] + rq[u], 0.0f);
            rowbuf[b * NPTS + it * FIT + ty * 8 + u] = __float_as_uint(d);
        }
    }
}

__global__ __launch_bounds__(256) void cf_reduce1(const unsigned* __restrict__ minbuf,
                                                  float* __restrict__ partial) {
    __shared__ float sm[4];
    const int base = blockIdx.x * 1024;
    float s = 0.0f;
    for (int k = threadIdx.x; k < 1024; k += 256)
        s += __uint_as_float(minbuf[base + k]);
#pragma unroll
    for (int off = 32; off > 0; off >>= 1)
        s += __shfl_down(s, off, 64);
    if ((threadIdx.x & 63) == 0) sm[threadIdx.x >> 6] = s;
    __syncthreads();
    if (threadIdx.x == 0)
        partial[blockIdx.x] = sm[0] + sm[1] + sm[2] + sm[3];
}

__global__ __launch_bounds__(256) void cf_reduce2(const float* __restrict__ partial,
                                                  float* __restrict__ out) {
    __shared__ float sm[4];
    float s = (threadIdx.x < 128) ? partial[threadIdx.x] : 0.f;
#pragma unroll
    for (int off = 32; off > 0; off >>= 1)
        s += __shfl_down(s, off, 64);
    if ((threadIdx.x & 63) == 0) sm[threadIdx.x >> 6] = s;
    __syncthreads();
    if (threadIdx.x == 0)
        out[0] = (sm[0] + sm[1] + sm[2] + sm[3]) * (1.0f / 64.0f);
}

extern "C" void kernel_launch(void* const* d_in, const int* in_sizes, int n_in,
                              void* d_out, int out_size, void* d_ws, size_t ws_size,
                              hipStream_t stream) {
    const float* preds = (const float*)d_in[0];
    const float* gts   = (const float*)d_in[1];
    const int*   idx   = (const int*)d_in[2];
    float* out = (float*)d_out;

    if (ws_size >= (size_t)WS_REQ) {
        float* rowpart = (float*)((char*)d_ws + OFF_ROW);
        float* colpart = (float*)((char*)d_ws + OFF_CPART);
        float* partial = (float*)((char*)d_ws + OFF_PART);
        unsigned short* qpk = (unsigned short*)((char*)d_ws + OFF_QPK);
        unsigned short* ypk = (unsigned short*)((char*)d_ws + OFF_YPK);
        cf_pack2<<<1024, 256, 0, stream>>>(preds, gts, idx, qpk, ypk);
        cf_mf3d<<<NB * 32, BLK, 0, stream>>>(qpk, ypk, rowpart, colpart);
        cf_reduce1n<<<256, 256, 0, stream>>>(rowpart, colpart, partial);
        cf_reduce2n<<<1, 256, 0, stream>>>(partial, out);
    } else {
        unsigned* minbuf = (unsigned*)d_ws;
        unsigned* colbuf = minbuf + NB * NPTS;
        float* partial   = (float*)((char*)d_ws + NMIN * 4);
        cf_init<<<(NB * NPTS) / 256, 256, 0, stream>>>(colbuf);
        cf_tile_lds<<<NB * (NPTS / FIT), BLK, 0, stream>>>(preds, gts, idx, minbuf);
        cf_reduce1<<<NMIN / 1024, 256, 0, stream>>>(minbuf, partial);
        cf_reduce2<<<1, 256, 0, stream>>>(partial, out);
    }
}

// Round 15
// 37.750 us; speedup vs baseline: 1.0775x; 1.0775x over previous
//
#include <hip/hip_runtime.h>

// ChamferLoss via 32x32x16 MFMA. P[i][j] = rx_i + ry_j - 2 x_i.y_j computed in one
// mfma_f32_32x32x16_bf16 per 32x32 tile via split-bf16 K-packing (13/16 slots):
//   A_k = [ah0..2, ah0..2, al0..2, rxh, rxl, 1, 1, 0,0,0]   (a = -2x, hi/lo split)
//   B_k = [yh0..2, yl0..2, yh0..2, 1, 1, ryh, ryl, 0,0,0]
// R15: pipeline slimming. A-fragments built IN REGISTERS from preds (qpk deleted);
// col mins -> global atomicMin colbuf (R12 proved atomics ~free; colpart's 16 MB
// round-trip deleted); reduce reads 1 MB not 9.5. Inner loop identical to R13
// (reg double-buffer + setprio). Grid back to 1024 (R14's 2048 regressed).

#define NPTS 2048
#define NB 64
#define BLK 256

#define PREDS_A 49152
#define PREDS_C 16384
#define GTS_A 6144
#define GTS_C 2048

// ---- ws layout ----
#define OFF_ROW   0                        // float rowbuf[64][2048]  = 512 KB
#define OFF_COL   524288                   // uint  colbuf[64][2048]  = 512 KB
#define OFF_PART  1048576                  // float partial[128]
#define OFF_YPK   1052672                  // ushort ypk: 64*2048*32B = 4 MB
#define WS_REQ    (OFF_YPK + NB * NPTS * 32)

using bf16x8  = __attribute__((ext_vector_type(8))) __bf16;
using short8v = __attribute__((ext_vector_type(8))) short;
using f32x16  = __attribute__((ext_vector_type(16))) float;

static __device__ __forceinline__ unsigned short f2bf(float f) {
    unsigned u = __float_as_uint(f);
    u = u + 0x7FFFu + ((u >> 16) & 1u);      // RNE
    return (unsigned short)(u >> 16);
}
static __device__ __forceinline__ float bf2f(unsigned short h) {
    return __uint_as_float(((unsigned)h) << 16);
}
static __device__ __forceinline__ float min3f(float a, float b, float c) {
    return fminf(fminf(a, b), c);            // clang fuses to v_min3_f32
}
static __device__ __forceinline__ float ctree(f32x16 a) {
    const float c0 = min3f(a[0], a[1], a[2]);
    const float c1 = min3f(a[3], a[4], a[5]);
    const float c2 = min3f(a[6], a[7], a[8]);
    const float c3 = min3f(a[9], a[10], a[11]);
    const float c4 = min3f(a[12], a[13], a[14]);
    const float d0 = min3f(c0, c1, a[15]);
    const float d1 = min3f(c2, c3, c4);
    return fminf(d0, d1);                    // 8 ops for 16 elems
}

// ---------- prep: init colbuf (512 blocks) + pack y (512 blocks) ----------
__global__ __launch_bounds__(256) void cf_prep(
    const float* __restrict__ gts, const int* __restrict__ idx,
    unsigned* __restrict__ colbuf, unsigned short* __restrict__ ypk)
{
    const int blk = blockIdx.x, tid = threadIdx.x;
    if (blk < 512) {
        colbuf[blk * 256 + tid] = 0x7F800000u;       // +inf
    } else {
        const unsigned short one = 0x3F80;
        const int p = (blk - 512) * 256 + tid;       // 0..131071
        const int b = p >> 11, j = p & 2047;
        const int i0 = idx[2 * b];
        const float* gb = gts + i0 * GTS_A + j;
        const float y0 = gb[0], y1 = gb[GTS_C], y2 = gb[2 * GTS_C];
        const float ry = fmaf(y0, y0, fmaf(y1, y1, y2 * y2));
        const unsigned short h0 = f2bf(y0), h1 = f2bf(y1), h2 = f2bf(y2);
        const unsigned short l0 = f2bf(y0 - bf2f(h0));
        const unsigned short l1 = f2bf(y1 - bf2f(h1));
        const unsigned short l2 = f2bf(y2 - bf2f(h2));
        const unsigned short rh = f2bf(ry), rl = f2bf(ry - bf2f(rh));
        alignas(16) unsigned short t[16] =
            {h0, h1, h2, l0, l1, l2, h0, h1, h2, one, one, rh, rl, 0, 0, 0};
        uint4* dst = (uint4*)(ypk + (size_t)p * 16);
        dst[0] = *(const uint4*)&t[0];
        dst[1] = *(const uint4*)&t[8];
    }
}

// ---------- main: grid = 64 b x 16 strips(128 rows); A packed in-register ----------
__global__ __launch_bounds__(BLK, 4) void cf_mf4(
    const float* __restrict__ preds, const int* __restrict__ idx,
    const unsigned short* __restrict__ ypk,
    float* __restrict__ rowbuf, unsigned* __restrict__ colbuf)
{
    const int tid = threadIdx.x;
    const int strip = blockIdx.x & 15;
    const int b = blockIdx.x >> 4;

    __shared__ float scolw[4][NPTS];         // 32 KB; every slot written exactly once

    const int l = tid & 63, w = tid >> 6;
    const int lc = l & 31, lh = l >> 5;

    // ---- in-register A-fragment: row strip*128 + w*32 + lc, k-half lh ----
    // layout must match verified qpk: {h0,h1,h2,h0,h1,h2,l0,l1 | l2,rh,rl,1,1,0,0,0}
    const int i0 = idx[2 * b], m1 = idx[2 * b + 1];
    {
    }
    const float* pb = preds + i0 * PREDS_A + m1 + (strip * 128 + w * 32 + lc) * 8;
    const float x0 = pb[0], x1 = pb[PREDS_C], x2 = pb[2 * PREDS_C];
    const float rx = fmaf(x0, x0, fmaf(x1, x1, x2 * x2));
    const float a0 = -2.f * x0, a1 = -2.f * x1, a2 = -2.f * x2;
    const unsigned short h0 = f2bf(a0), h1 = f2bf(a1), h2 = f2bf(a2);
    const unsigned short lo0 = f2bf(a0 - bf2f(h0));
    const unsigned short lo1 = f2bf(a1 - bf2f(h1));
    const unsigned short lo2 = f2bf(a2 - bf2f(h2));
    const unsigned short rh = f2bf(rx), rl = f2bf(rx - bf2f(rh));
    const unsigned short one = 0x3F80;
    short8v av;
    av[0] = (short)(lh ? lo2 : h0);
    av[1] = (short)(lh ? rh  : h1);
    av[2] = (short)(lh ? rl  : h2);
    av[3] = (short)(lh ? one : h0);
    av[4] = (short)(lh ? one : h1);
    av[5] = (short)(lh ? (unsigned short)0 : h2);
    av[6] = (short)(lh ? (unsigned short)0 : lo0);
    av[7] = (short)(lh ? (unsigned short)0 : lo1);
    const bf16x8 afrag = __builtin_bit_cast(bf16x8, av);

    float rm[16];
#pragma unroll
    for (int r = 0; r < 16; ++r) rm[r] = INFINITY;

    const f32x16 z = {0.f, 0.f, 0.f, 0.f, 0.f, 0.f, 0.f, 0.f,
                      0.f, 0.f, 0.f, 0.f, 0.f, 0.f, 0.f, 0.f};

    const short8v* yp = (const short8v*)ypk + (b * NPTS * 2 + lc * 2 + lh);

    // prologue: first B pair in flight
    bf16x8 curA = __builtin_bit_cast(bf16x8, yp[0]);
    bf16x8 curB = __builtin_bit_cast(bf16x8, yp[64]);

#pragma unroll 2
    for (int s = 0; s < 32; ++s) {
        const int nidx = (s < 31) ? (2 * s + 2) * 64 : 0;
        const bf16x8 nxtA = __builtin_bit_cast(bf16x8, yp[nidx]);
        const bf16x8 nxtB = __builtin_bit_cast(bf16x8, yp[nidx + 64]);

        __builtin_amdgcn_s_setprio(1);
        f32x16 accA = __builtin_amdgcn_mfma_f32_32x32x16_bf16(afrag, curA, z, 0, 0, 0);
        f32x16 accB = __builtin_amdgcn_mfma_f32_32x32x16_bf16(afrag, curB, z, 0, 0, 0);
        __builtin_amdgcn_s_setprio(0);

        // rows: 16 min3 per tile pair (0.5 op/elem), register-resident
#pragma unroll
        for (int r = 0; r < 16; ++r) rm[r] = min3f(accA[r], accB[r], rm[r]);
        // cols: in-lane tree, merge k-halves via shfl, plain ds_write (dup benign)
        float cmA = ctree(accA);
        float cmB = ctree(accB);
        cmA = fminf(cmA, __shfl_xor(cmA, 32, 64));
        cmB = fminf(cmB, __shfl_xor(cmB, 32, 64));
        scolw[w][(2 * s) * 32 + lc] = cmA;
        scolw[w][(2 * s + 1) * 32 + lc] = cmB;

        curA = nxtA; curB = nxtB;
    }

    // ---- row flush: butterfly over 32 col-lanes, exclusive float store ----
#pragma unroll
    for (int r = 0; r < 16; ++r) {
        float v = rm[r];
        v = fminf(v, __shfl_xor(v, 1, 32));
        v = fminf(v, __shfl_xor(v, 2, 32));
        v = fminf(v, __shfl_xor(v, 4, 32));
        v = fminf(v, __shfl_xor(v, 8, 32));
        v = fminf(v, __shfl_xor(v, 16, 32));
        rm[r] = v;
    }
    if (lc == 0) {
        const int rbase = b * NPTS + strip * 128 + w * 32 + 4 * lh;
#pragma unroll
        for (int r = 0; r < 16; ++r)
            rowbuf[rbase + (r & 3) + 8 * (r >> 2)] = fmaxf(rm[r], 0.f);
    }

    // ---- col flush: min over 4 waves, one global atomicMin per col ----
    __syncthreads();
    for (int k = tid; k < NPTS; k += BLK) {
        const float m = fminf(fminf(scolw[0][k], scolw[1][k]),
                              fminf(scolw[2][k], scolw[3][k]));
        atomicMin(&colbuf[b * NPTS + k], __float_as_uint(fmaxf(m, 0.f)));
    }
}

// ---------- reduce: blocks 0-63 rows, 64-127 cols; 2048 elems each ----------
__global__ __launch_bounds__(256) void cf_red1(
    const float* __restrict__ rowbuf, const unsigned* __restrict__ colbuf,
    float* __restrict__ partial)
{
    __shared__ float sm[4];
    const int blk = blockIdx.x, tid = threadIdx.x;
    float s = 0.0f;
    if (blk < 64) {
        const float* rp = rowbuf + blk * 2048;
#pragma unroll
        for (int i = 0; i < 8; ++i) s += rp[tid + i * 256];
    } else {
        const unsigned* cp = colbuf + (blk - 64) * 2048;
#pragma unroll
        for (int i = 0; i < 8; ++i) s += __uint_as_float(cp[tid + i * 256]);
    }
#pragma unroll
    for (int off = 32; off > 0; off >>= 1)
        s += __shfl_down(s, off, 64);
    if ((tid & 63) == 0) sm[tid >> 6] = s;
    __syncthreads();
    if (tid == 0) partial[blk] = sm[0] + sm[1] + sm[2] + sm[3];
}

__global__ __launch_bounds__(256) void cf_red2(const float* __restrict__ partial,
                                               float* __restrict__ out) {
    __shared__ float sm[4];
    float s = (threadIdx.x < 128) ? partial[threadIdx.x] : 0.f;
#pragma unroll
    for (int off = 32; off > 0; off >>= 1)
        s += __shfl_down(s, off, 64);
    if ((threadIdx.x & 63) == 0) sm[threadIdx.x >> 6] = s;
    __syncthreads();
    if (threadIdx.x == 0)
        out[0] = (sm[0] + sm[1] + sm[2] + sm[3]) * (1.0f / 64.0f);
}

// ================= fallback (proven R6 path, uint-atomic based) =================
#define NMIN (2 * NB * NPTS)
#define FIT 128
#define FJT 128
#define PADI(j) ((j) + ((j) >> 4))

__global__ __launch_bounds__(256) void cf_init(unsigned* __restrict__ colbuf) {
    int i = blockIdx.x * 256 + threadIdx.x;
    colbuf[i] = 0x7F800000u;
}

__global__ __launch_bounds__(BLK, 4) void cf_tile_lds(
    const float* __restrict__ preds, const float* __restrict__ gts,
    const int* __restrict__ idx, unsigned* __restrict__ minbuf)
{
    const int tid = threadIdx.x;
    const int bid = blockIdx.x;
    const int it = bid & 15;
    const int b = bid >> 4;
    const int i0 = idx[2 * b];
    const int m1 = idx[2 * b + 1];
    const float* pbase = preds + i0 * PREDS_A + m1;
    const float* gbase = gts + i0 * GTS_A;

    __shared__ float4 sq[PADI(FIT - 1) + 2];
    __shared__ float4 sr[PADI(NPTS - 1) + 2];
    __shared__ float  scolw[4][FJT];

    if (tid < FIT) {
        const int i = it * FIT + tid;
        const float q0 = pbase[i * 8];
        const float q1 = pbase[i * 8 + PREDS_C];
        const float q2 = pbase[i * 8 + 2 * PREDS_C];
        const float rq = fmaf(q0, q0, fmaf(q1, q1, q2 * q2));
        sq[PADI(tid)] = make_float4(-2.f * q0, -2.f * q1, -2.f * q2, rq);
    }
#pragma unroll
    for (int k = 0; k < 8; ++k) {
        const int j = tid + BLK * k;
        const float r0 = gbase[j];
        const float r1 = gbase[j + GTS_C];
        const float r2 = gbase[j + 2 * GTS_C];
        const float rr = fmaf(r0, r0, fmaf(r1, r1, r2 * r2));
        sr[PADI(j)] = make_float4(r0, r1, r2, rr);
    }
    __syncthreads();

    const int ty = tid >> 4, tx = tid & 15;
    float nq0[8], nq1[8], nq2[8], rq[8], rmin[8];
#pragma unroll
    for (int u = 0; u < 8; ++u) {
        const float4 q = sq[PADI(ty * 8 + u)];
        nq0[u] = q.x; nq1[u] = q.y; nq2[u] = q.z; rq[u] = q.w;
        rmin[u] = INFINITY;
    }
    unsigned* rowbuf = minbuf;
    unsigned* colbuf = minbuf + NB * NPTS;

    for (int jt = 0; jt < NPTS / FJT; ++jt) {
        float4 r[8];
        const int rb = PADI(jt * FJT + tx * 8);
#pragma unroll
        for (int v = 0; v < 8; ++v) r[v] = sr[rb + v];
        float cmin[8];
#pragma unroll
        for (int v = 0; v < 8; ++v) cmin[v] = INFINITY;
#pragma unroll
        for (int v = 0; v < 8; v += 2) {
#pragma unroll
            for (int u = 0; u < 8; u += 2) {
                float s00 = fmaf(nq2[u], r[v].z, r[v].w);
                s00 = fmaf(nq1[u], r[v].y, s00);
                s00 = fmaf(nq0[u], r[v].x, s00);
                float s01 = fmaf(nq2[u], r[v + 1].z, r[v + 1].w);
                s01 = fmaf(nq1[u], r[v + 1].y, s01);
                s01 = fmaf(nq0[u], r[v + 1].x, s01);
                float s10 = fmaf(nq2[u + 1], r[v].z, r[v].w);
                s10 = fmaf(nq1[u + 1], r[v].y, s10);
                s10 = fmaf(nq0[u + 1], r[v].x, s10);
                float s11 = fmaf(nq2[u + 1], r[v + 1].z, r[v + 1].w);
                s11 = fmaf(nq1[u + 1], r[v + 1].y, s11);
                s11 = fmaf(nq0[u + 1], r[v + 1].x, s11);
                rmin[u]     = min3f(s00, s01, rmin[u]);
                rmin[u + 1] = min3f(s10, s11, rmin[u + 1]);
                const float d00 = s00 + rq[u];
                const float d10 = s10 + rq[u + 1];
                const float d01 = s01 + rq[u];
                const float d11 = s11 + rq[u + 1];
                cmin[v]     = min3f(d00, d10, cmin[v]);
                cmin[v + 1] = min3f(d01, d11, cmin[v + 1]);
            }
        }
#pragma unroll
        for (int v = 0; v < 8; ++v) {
            float c = cmin[v];
            c = fminf(c, __shfl_xor(c, 16, 64));
            c = fminf(c, __shfl_xor(c, 32, 64));
            cmin[v] = c;
        }
        if (((tid >> 4) & 3) == 0) {
            const int w = tid >> 6;
            *(float4*)&scolw[w][tx * 8]     = make_float4(cmin[0], cmin[1], cmin[2], cmin[3]);
            *(float4*)&scolw[w][tx * 8 + 4] = make_float4(cmin[4], cmin[5], cmin[6], cmin[7]);
        }
        __syncthreads();
        if (tid < FJT) {
            float m = fminf(min3f(scolw[0][tid], scolw[1][tid], scolw[2][tid]), scolw[3][tid]);
            m = fmaxf(m, 0.0f);
            atomicMin(&colbuf[b * NPTS + jt * FJT + tid], __float_as_uint(m));
        }
        __syncthreads();
    }
#pragma unroll
    for (int u = 0; u < 8; ++u) {
        float rm = rmin[u];
        rm = fminf(rm, __shfl_xor(rm, 1, 16));
        rm = fminf(rm, __shfl_xor(rm, 2, 16));
        rm = fminf(rm, __shfl_xor(rm, 4, 16));
        rm = fminf(rm, __shfl_xor(rm, 8, 16));
        rmin[u] = rm;
    }
    if (tx == 0) {
#pragma unroll
        for (int u = 0; u < 8; ++u) {
            const float d = fmaxf(rmin[u] + rq[u], 0.0f);
            rowbuf[b * NPTS + it * FIT + ty * 8 + u] = __float_as_uint(d);
        }
    }
}

__global__ __launch_bounds__(256) void cf_reduce1(const unsigned* __restrict__ minbuf,
                                                  float* __restrict__ partial) {
    __shared__ float sm[4];
    const int base = blockIdx.x * 1024;
    float s = 0.0f;
    for (int k = threadIdx.x; k < 1024; k += 256)
        s += __uint_as_float(minbuf[base + k]);
#pragma unroll
    for (int off = 32; off > 0; off >>= 1)
        s += __shfl_down(s, off, 64);
    if ((threadIdx.x & 63) == 0) sm[threadIdx.x >> 6] = s;
    __syncthreads();
    if (threadIdx.x == 0)
        partial[blockIdx.x] = sm[0] + sm[1] + sm[2] + sm[3];
}

__global__ __launch_bounds__(256) void cf_reduce2(const float* __restrict__ partial,
                                                  float* __restrict__ out) {
    __shared__ float sm[4];
    float s = (threadIdx.x < 128) ? partial[threadIdx.x] : 0.f;
#pragma unroll
    for (int off = 32; off > 0; off >>= 1)
        s += __shfl_down(s, off, 64);
    if ((threadIdx.x & 63) == 0) sm[threadIdx.x >> 6] = s;
    __syncthreads();
    if (threadIdx.x == 0)
        out[0] = (sm[0] + sm[1] + sm[2] + sm[3]) * (1.0f / 64.0f);
}

extern "C" void kernel_launch(void* const* d_in, const int* in_sizes, int n_in,
                              void* d_out, int out_size, void* d_ws, size_t ws_size,
                              hipStream_t stream) {
    const float* preds = (const float*)d_in[0];
    const float* gts   = (const float*)d_in[1];
    const int*   idx   = (const int*)d_in[2];
    float* out = (float*)d_out;

    if (ws_size >= (size_t)WS_REQ) {
        float*    rowbuf  = (float*)((char*)d_ws + OFF_ROW);
        unsigned* colbuf  = (unsigned*)((char*)d_ws + OFF_COL);
        float*    partial = (float*)((char*)d_ws + OFF_PART);
        unsigned short* ypk = (unsigned short*)((char*)d_ws + OFF_YPK);
        cf_prep<<<1024, 256, 0, stream>>>(gts, idx, colbuf, ypk);
        cf_mf4<<<NB * 16, BLK, 0, stream>>>(preds, idx, ypk, rowbuf, colbuf);
        cf_red1<<<128, 256, 0, stream>>>(rowbuf, colbuf, partial);
        cf_red2<<<1, 256, 0, stream>>>(partial, out);
    } else {
        unsigned* minbuf = (unsigned*)d_ws;
        unsigned* colbuf = minbuf + NB * NPTS;
        float* partial   = (float*)((char*)d_ws + NMIN * 4);
        cf_init<<<(NB * NPTS) / 256, 256, 0, stream>>>(colbuf);
        cf_tile_lds<<<NB * (NPTS / FIT), BLK, 0, stream>>>(preds, gts, idx, minbuf);
        cf_reduce1<<<NMIN / 1024, 256, 0, stream>>>(minbuf, partial);
        cf_reduce2<<<1, 256, 0, stream>>>(partial, out);
    }
}